// Round 1
// 272.726 us; speedup vs baseline: 1.3035x; 1.3035x over previous
//
#include <hip/hip_runtime.h>

typedef __bf16 bf16x8 __attribute__((ext_vector_type(8)));
typedef float  f32x4  __attribute__((ext_vector_type(4)));
typedef unsigned int u32x4 __attribute__((ext_vector_type(4)));

#define B_   2
#define N_   512
#define ND_  256
#define ED_  64
#define NH_  8
#define DH_  32

static __device__ __forceinline__ unsigned pack_bf16(float a, float b) {
    unsigned short ua = __builtin_bit_cast(unsigned short, (__bf16)a);
    unsigned short ub = __builtin_bit_cast(unsigned short, (__bf16)b);
    return (unsigned)ua | ((unsigned)ub << 16);
}

// ---------------- prep kernel 1: edge-weight fp32 -> bf16 (row-major [256][64])
__global__ __launch_bounds__(256) void cvt_w_kernel(
    const float* __restrict__ wq, const float* __restrict__ wk,
    const float* __restrict__ wv, unsigned short* __restrict__ w16)
{
    int id = blockIdx.x * 256 + threadIdx.x;          // 0..49151
    const float* src = (id < 16384) ? wq : (id < 32768 ? wk : wv);
    int idx = id & 16383;
    w16[id] = __builtin_bit_cast(unsigned short, (__bf16)src[idx]);
}

// ---------------- prep kernel 1b: transpose node weights -> Wt[m][k][c] fp32
__global__ __launch_bounds__(256) void trans_w_kernel(
    const float* __restrict__ Wq, const float* __restrict__ Wk,
    const float* __restrict__ Wv, float* __restrict__ Wt)
{
    __shared__ float t[32][33];
    const int bx = blockIdx.x;        // 0..191 = 3 mats * 64 tiles
    const int m  = bx >> 6;
    const int t6 = bx & 63;
    const int cb = (t6 >> 3) << 5;    // c-block
    const int kb = (t6 & 7) << 5;     // k-block
    const float* W = (m == 0) ? Wq : (m == 1 ? Wk : Wv);
    const int tx = threadIdx.x & 31, ty = threadIdx.x >> 5;   // 32 x 8
    #pragma unroll
    for (int s = 0; s < 4; s++)
        t[ty + 8 * s][tx] = W[(size_t)(cb + ty + 8 * s) * ND_ + kb + tx];
    __syncthreads();
    float* dst = Wt + (size_t)m * ND_ * ND_;
    #pragma unroll
    for (int s = 0; s < 4; s++)
        dst[(size_t)(kb + ty + 8 * s) * ND_ + cb + tx] = t[tx][ty + 8 * s];
}

// ------- prep kernel 2: node projections with coalesced (transposed) weights.
// Q -> row-major head-split Qh[bh][i][32].
// K,V -> KVp in MFMA C-fragment order so attn loads are lane-linear:
//   KVp float idx = ((bh*32 + j/16)*4 + set)*256 + (((d>>2)&3)*16 + (j&15))*4 + (d&3)
//   set: 0,1 = K halves (d<16 / d>=16), 2,3 = V halves.
__global__ __launch_bounds__(256) void qkv_kernel(
    const float* __restrict__ node, const float* __restrict__ Wt,
    const float* __restrict__ bnq, const float* __restrict__ bnk,
    const float* __restrict__ bnv, const float* __restrict__ beq,
    const float* __restrict__ bek, const float* __restrict__ bev,
    float* __restrict__ Qh, float* __restrict__ KVp)
{
    __shared__ float xs[4][ND_];
    const int c   = threadIdx.x;
    const int m   = blockIdx.x >> 8;       // 0=Q 1=K 2=V
    const int grp = blockIdx.x & 255;
    const int g0  = grp * 4;
    {
        const int r = c >> 6, col4 = (c & 63) * 4;
        const float4 v = *reinterpret_cast<const float4*>(node + (size_t)(g0 + r) * ND_ + col4);
        *reinterpret_cast<float4*>(&xs[r][col4]) = v;
    }
    __syncthreads();

    const float* Wm = Wt + (size_t)m * ND_ * ND_;
    float acc[4] = {0.f, 0.f, 0.f, 0.f};
    for (int k = 0; k < ND_; k += 4) {
        const float w0 = Wm[(size_t)(k + 0) * ND_ + c];
        const float w1 = Wm[(size_t)(k + 1) * ND_ + c];
        const float w2 = Wm[(size_t)(k + 2) * ND_ + c];
        const float w3 = Wm[(size_t)(k + 3) * ND_ + c];
        #pragma unroll
        for (int rr = 0; rr < 4; rr++) {
            const float4 x = *reinterpret_cast<const float4*>(&xs[rr][k]);
            acc[rr] += x.x * w0 + x.y * w1 + x.z * w2 + x.w * w3;
        }
    }
    const float bias = (m == 0) ? (bnq[c] + beq[c])
                     : (m == 1) ? (bnk[c] + bek[c])
                                : (bnv[c] + bev[c]);
    const int h = c >> 5, d = c & 31;
    #pragma unroll
    for (int rr = 0; rr < 4; rr++) {
        const int g  = g0 + rr;
        const int bb = g >> 9, ii = g & (N_ - 1);
        const int bh = bb * NH_ + h;
        const float y = acc[rr] + bias;
        if (m == 0) {
            Qh[((size_t)bh * N_ + ii) * DH_ + d] = y;
        } else {
            const int set = ((m == 1) ? 0 : 2) + (d >> 4);
            const size_t idx = (((size_t)bh * 32 + (ii >> 4)) * 4 + set) * 256
                             + (size_t)((((d >> 2) & 3) * 16 + (ii & 15)) * 4 + (d & 3));
            KVp[idx] = y;
        }
    }
}

// ---------------- main fused kernel: one block per (b, i-pair), 8 waves = 8 heads.
// TWO query rows per block: K/V loads (i-independent) amortize 2x, per-wave ILP 2x.
// K/V loads are lane-linear (fragment layout) and depth-1 prefetched so every
// consumed vmem group is the oldest outstanding (no vmcnt convoy behind the
// HBM edge-staging loads).
__global__ __launch_bounds__(512, 2) void attn_kernel(
    const float* __restrict__ edge,
    const float* __restrict__ Qh, const float* __restrict__ KVp,
    const unsigned short* __restrict__ W16, float* __restrict__ out)
{
    __shared__ unsigned short lds_[2][2][64 * 72];   // [buf][i-row][64 rows * 72]

    const int tid  = threadIdx.x;
    const int lane = tid & 63;
    const int h    = tid >> 6;       // wave id == head
    const int q4   = lane >> 4;
    const int l15  = lane & 15;
    const int blk  = blockIdx.x;     // 0..511
    const int b    = blk >> 8;
    const int i0   = (blk & 255) * 2;
    const int bh   = b * NH_ + h;

    // W A-operand frags: A[m=l15][k=q4*8+kk]; wf[m][half][ks]
    bf16x8 wf[3][2][2];
    #pragma unroll
    for (int m = 0; m < 3; m++)
        #pragma unroll
        for (int hf = 0; hf < 2; hf++)
            #pragma unroll
            for (int ks = 0; ks < 2; ks++) {
                const u32x4* p = reinterpret_cast<const u32x4*>(
                    W16 + m * (ND_ * ED_) + (h * DH_ + hf * 16 + l15) * ED_ + ks * 32 + q4 * 8);
                wf[m][hf][ks] = __builtin_bit_cast(bf16x8, *p);
            }

    // Q C-init (row d = q4*4+r, broadcast over j=l15), for both i rows
    f32x4 Cq[2][2];
    {
        const float* Qrow = Qh + ((size_t)bh * N_ + i0) * DH_;
        Cq[0][0] = *reinterpret_cast<const f32x4*>(Qrow + q4 * 4);
        Cq[0][1] = *reinterpret_cast<const f32x4*>(Qrow + 16 + q4 * 4);
        Cq[1][0] = *reinterpret_cast<const f32x4*>(Qrow + DH_ + q4 * 4);
        Cq[1][1] = *reinterpret_cast<const f32x4*>(Qrow + DH_ + 16 + q4 * 4);
    }

    // lane-linear K/V fragment base: per jg, sets at +0,+64,+128,+192 (f32x4)
    const f32x4* kvb = reinterpret_cast<const f32x4*>(KVp + (size_t)bh * 32 * 1024) + lane;

    const float* eb0 = edge + ((size_t)(b * N_ + i0)) * N_ * ED_;
    const float* eb1 = eb0 + (size_t)N_ * ED_;

    float l_acc[2] = {0.f, 0.f};
    f32x4 o0[2] = {{0.f,0.f,0.f,0.f},{0.f,0.f,0.f,0.f}};
    f32x4 o1[2] = {{0.f,0.f,0.f,0.f},{0.f,0.f,0.f,0.f}};
    const float scale = 0.17677669529663687f;   // 1/sqrt(32)

    // stage chunk 0 for both i rows (each: 64 j-rows = 4096 floats)
    float4 g[2][2];
    {
        const float4* e0 = reinterpret_cast<const float4*>(eb0);
        const float4* e1 = reinterpret_cast<const float4*>(eb1);
        g[0][0] = e0[tid]; g[0][1] = e0[tid + 512];
        g[1][0] = e1[tid]; g[1][1] = e1[tid + 512];
    }
    #pragma unroll
    for (int ii = 0; ii < 2; ii++) {
        unsigned short* buf = lds_[0][ii];
        #pragma unroll
        for (int pt = 0; pt < 2; pt++) {
            const float4 gg = g[ii][pt];
            const int f = tid + pt * 512;
            const int row = f >> 4, c4 = f & 15;
            uint2 v = {pack_bf16(gg.x, gg.y), pack_bf16(gg.z, gg.w)};
            *reinterpret_cast<uint2*>(buf + row * 72 + c4 * 4) = v;
        }
    }
    // prefetch K/V for jg = 0
    f32x4 kn0 = kvb[0], kn1 = kvb[64], vn0 = kvb[128], vn1 = kvb[192];
    __syncthreads();

    #pragma unroll 1
    for (int ch = 0; ch < 8; ch++) {
        if (ch < 7) {   // issue next chunk's staging loads (consumed at chunk end)
            const float4* e0 = reinterpret_cast<const float4*>(eb0 + (ch + 1) * 4096);
            const float4* e1 = reinterpret_cast<const float4*>(eb1 + (ch + 1) * 4096);
            g[0][0] = e0[tid]; g[0][1] = e0[tid + 512];
            g[1][0] = e1[tid]; g[1][1] = e1[tid + 512];
        }
        const unsigned short* buf0 = lds_[ch & 1][0];
        const unsigned short* buf1 = lds_[ch & 1][1];

        #pragma unroll 2
        for (int sub = 0; sub < 4; sub++) {
            const int jg = ch * 4 + sub;
            // consume previously-prefetched K/V (oldest outstanding vmem group)
            const f32x4 Ck0 = kn0, Ck1 = kn1, Cv0 = vn0, Cv1 = vn1;
            {   // prefetch next jg (wraps harmlessly at the end)
                const f32x4* p = kvb + ((jg + 1) & 31) * 256;
                kn0 = p[0]; kn1 = p[64]; vn0 = p[128]; vn1 = p[192];
            }
            const unsigned short* ar0 = buf0 + (sub * 16 + l15) * 72 + q4 * 8;
            const unsigned short* ar1 = buf1 + (sub * 16 + l15) * 72 + q4 * 8;
            const bf16x8 a00 = __builtin_bit_cast(bf16x8, *reinterpret_cast<const u32x4*>(ar0));
            const bf16x8 a01 = __builtin_bit_cast(bf16x8, *reinterpret_cast<const u32x4*>(ar0 + 32));
            const bf16x8 a10 = __builtin_bit_cast(bf16x8, *reinterpret_cast<const u32x4*>(ar1));
            const bf16x8 a11 = __builtin_bit_cast(bf16x8, *reinterpret_cast<const u32x4*>(ar1 + 32));

            #pragma unroll
            for (int ii = 0; ii < 2; ii++) {
                const bf16x8 aA = ii ? a10 : a00;
                const bf16x8 aB = ii ? a11 : a01;
                f32x4 eq0 = __builtin_amdgcn_mfma_f32_16x16x32_bf16(wf[0][0][0], aA, Cq[ii][0], 0, 0, 0);
                f32x4 eq1 = __builtin_amdgcn_mfma_f32_16x16x32_bf16(wf[0][1][0], aA, Cq[ii][1], 0, 0, 0);
                f32x4 ek0 = __builtin_amdgcn_mfma_f32_16x16x32_bf16(wf[1][0][0], aA, Ck0, 0, 0, 0);
                f32x4 ek1 = __builtin_amdgcn_mfma_f32_16x16x32_bf16(wf[1][1][0], aA, Ck1, 0, 0, 0);
                f32x4 ev0 = __builtin_amdgcn_mfma_f32_16x16x32_bf16(wf[2][0][0], aA, Cv0, 0, 0, 0);
                f32x4 ev1 = __builtin_amdgcn_mfma_f32_16x16x32_bf16(wf[2][1][0], aA, Cv1, 0, 0, 0);
                eq0 = __builtin_amdgcn_mfma_f32_16x16x32_bf16(wf[0][0][1], aB, eq0, 0, 0, 0);
                eq1 = __builtin_amdgcn_mfma_f32_16x16x32_bf16(wf[0][1][1], aB, eq1, 0, 0, 0);
                ek0 = __builtin_amdgcn_mfma_f32_16x16x32_bf16(wf[1][0][1], aB, ek0, 0, 0, 0);
                ek1 = __builtin_amdgcn_mfma_f32_16x16x32_bf16(wf[1][1][1], aB, ek1, 0, 0, 0);
                ev0 = __builtin_amdgcn_mfma_f32_16x16x32_bf16(wf[2][0][1], aB, ev0, 0, 0, 0);
                ev1 = __builtin_amdgcn_mfma_f32_16x16x32_bf16(wf[2][1][1], aB, ev1, 0, 0, 0);

                // score for lane's j (quad-reduce over d), then unnormalized exp
                float ta = eq0[0]*ek0[0] + eq0[1]*ek0[1];
                float tb = eq0[2]*ek0[2] + eq0[3]*ek0[3];
                float tc = eq1[0]*ek1[0] + eq1[1]*ek1[1];
                float td = eq1[2]*ek1[2] + eq1[3]*ek1[3];
                float t = (ta + tb) + (tc + td);
                t += __shfl_xor(t, 16, 64);
                t += __shfl_xor(t, 32, 64);
                const float p = __expf(fmaf(t, scale, -4.f));   // shift cancels in norm

                l_acc[ii] += p;
                o0[ii] += ev0 * p;
                o1[ii] += ev1 * p;
            }
        }

        if (ch < 7) {   // pack+store next chunk into the other buffer
            #pragma unroll
            for (int ii = 0; ii < 2; ii++) {
                unsigned short* nbuf = lds_[(ch + 1) & 1][ii];
                #pragma unroll
                for (int pt = 0; pt < 2; pt++) {
                    const float4 gg = g[ii][pt];
                    const int f = tid + pt * 512;
                    const int row = f >> 4, c4 = f & 15;
                    uint2 v = {pack_bf16(gg.x, gg.y), pack_bf16(gg.z, gg.w)};
                    *reinterpret_cast<uint2*>(nbuf + row * 72 + c4 * 4) = v;
                }
            }
        }
        __syncthreads();
    }

    // final reductions over the 16 j-classes (l15)
    #pragma unroll
    for (int mask = 1; mask <= 8; mask <<= 1) {
        #pragma unroll
        for (int ii = 0; ii < 2; ii++) {
            l_acc[ii] += __shfl_xor(l_acc[ii], mask, 64);
            #pragma unroll
            for (int r = 0; r < 4; r++) {
                o0[ii][r] += __shfl_xor(o0[ii][r], mask, 64);
                o1[ii][r] += __shfl_xor(o1[ii][r], mask, 64);
            }
        }
    }
    if (l15 == 0) {
        #pragma unroll
        for (int ii = 0; ii < 2; ii++) {
            const float inv = 1.f / l_acc[ii];
            float* orow = out + ((size_t)(b * N_ + i0 + ii)) * ND_ + h * DH_ + q4 * 4;
            float4 va = {o0[ii][0] * inv, o0[ii][1] * inv, o0[ii][2] * inv, o0[ii][3] * inv};
            float4 vb = {o1[ii][0] * inv, o1[ii][1] * inv, o1[ii][2] * inv, o1[ii][3] * inv};
            *reinterpret_cast<float4*>(orow)      = va;
            *reinterpret_cast<float4*>(orow + 16) = vb;
        }
    }
}

extern "C" void kernel_launch(void* const* d_in, const int* in_sizes, int n_in,
                              void* d_out, int out_size, void* d_ws, size_t ws_size,
                              hipStream_t stream) {
    const float* node = (const float*)d_in[0];
    const float* edge = (const float*)d_in[1];
    const float* Wnq  = (const float*)d_in[2];
    const float* bnq  = (const float*)d_in[3];
    const float* Wnk  = (const float*)d_in[4];
    const float* bnk  = (const float*)d_in[5];
    const float* Wnv  = (const float*)d_in[6];
    const float* bnv  = (const float*)d_in[7];
    const float* Weq  = (const float*)d_in[8];
    const float* beq  = (const float*)d_in[9];
    const float* Wek  = (const float*)d_in[10];
    const float* bek  = (const float*)d_in[11];
    const float* Wev  = (const float*)d_in[12];
    const float* bev  = (const float*)d_in[13];

    char* ws = (char*)d_ws;
    unsigned short* W16 = (unsigned short*)ws;              // 96 KB (pad to 128 KB)
    float* Wt  = (float*)(ws + 131072);                     // 768 KB
    float* Qh  = (float*)(ws + 131072 + 786432);            // 1 MB
    float* KVp = (float*)(ws + 131072 + 786432 + 1048576);  // 2 MB
    float* out = (float*)d_out;

    cvt_w_kernel<<<192, 256, 0, stream>>>(Weq, Wek, Wev, W16);
    trans_w_kernel<<<192, 256, 0, stream>>>(Wnq, Wnk, Wnv, Wt);
    qkv_kernel<<<768, 256, 0, stream>>>(node, Wt, bnq, bnk, bnv, beq, bek, bev, Qh, KVp);
    attn_kernel<<<512, 512, 0, stream>>>(edge, Qh, KVp, W16, out);
}